// Round 16
// baseline (132.646 us; speedup 1.0000x reference)
//
#include <hip/hip_runtime.h>
#include <hip/hip_fp16.h>

#define IMG   512
#define TW    32
#define TH    64
#define WS    11
#define NP    96
#define NSLOT 256
#define PR2   37            // H pair-rows (74 rows as f16 pairs)
#define RSTR  32            // u32 row stride
#define PLANE (PR2*RSTR)

typedef _Float16 f16x8 __attribute__((ext_vector_type(8)));
typedef float    f32x16 __attribute__((ext_vector_type(16)));
typedef _Float16 h2v   __attribute__((ext_vector_type(2)));

#define GAUSS_W { \
    0.00102837990674f, 0.00759883148699f, 0.03600079242909f, \
    0.10936069869137f, 0.21300538108707f, 0.26601190869814f, \
    0.21300538108707f, 0.10936069869137f, 0.03600079242909f, \
    0.00759883148699f, 0.00102837990674f }

static __device__ __forceinline__ uint pkh(float a, float b) {
    return __builtin_bit_cast(uint, __builtin_amdgcn_cvt_pkrtz(a, b));
}
static __device__ __forceinline__ ushort f2h(float x) {
    return __builtin_bit_cast(ushort, (_Float16)x);
}
static __device__ __forceinline__ float h2f(ushort u) {
    return (float)__builtin_bit_cast(_Float16, u);
}
static __device__ __forceinline__ uint pkmul(uint a, uint b) {
    const h2v r = __builtin_bit_cast(h2v, a) * __builtin_bit_cast(h2v, b); // v_pk_mul_f16
    return __builtin_bit_cast(uint, r);
}

#define DOT(ACC, VW, WT) \
    asm("v_dot2_f32_f16 %0, %1, %2, %0" : "+v"(ACC) : "v"(VW), "v"(WT))

// Precompute the horizontal band-matrix B-fragments (f16 MFMA B-layout):
// B[k][j] = Wf16[k - j - 3]; lane l holds B[16T+8*(l>>5)+2*w4+{0,1}][l&31].
// gwB[(T*64+lane)*4 + w4] — validated layout (R15 built these in-thread; same values).
__global__ void build_gh(uint* __restrict__ gwB) {
    constexpr float W[WS] = GAUSS_W;
    const int lane = threadIdx.x;   // 64 threads
    const int col  = lane & 31;
    const int h    = lane >> 5;
    for (int T = 0; T < 3; ++T) {
        for (int w4 = 0; w4 < 4; ++w4) {
            const int t0 = 16*T + 8*h + 2*w4 - col - 3;
            const ushort b0 = (t0 >= 0     && t0 < WS)     ? f2h(W[t0])     : (ushort)0;
            const ushort b1 = (t0 + 1 >= 0 && t0 + 1 < WS) ? f2h(W[t0 + 1]) : (ushort)0;
            gwB[(T * 64 + lane) * 4 + w4] = (uint)b0 | ((uint)b1 << 16);
        }
    }
}

__global__ __launch_bounds__(256, 5) void ssim_main(const float* __restrict__ img1,
                                                    const float* __restrict__ img2,
                                                    const uint* __restrict__ gwB,
                                                    double* __restrict__ acc) {
    constexpr float W[WS] = GAUSS_W;

    // H signals, f16 row-pairs: HP[(s*PR2+p)*32 + col] = h(H[2p][col]) | h(H[2p+1][col])<<16
    __shared__ uint HP[5 * PLANE];   // 23,680 B

    const int tid  = threadIdx.x;
    const int wid  = tid >> 6;
    const int col  = tid & 31;
    const int h    = (tid >> 5) & 1;
    const int lane = tid & 63;
    const int bx = blockIdx.x;       // 0..15
    const int by = blockIdx.y;       // 0..7
    const float* p1 = img1 + (size_t)blockIdx.z * (IMG * IMG);
    const float* p2 = img2 + (size_t)blockIdx.z * (IMG * IMG);

    // f16 weights; pe/po pair-words for the vertical dot2; alpha = f16 weight sum
    ushort us[12];
    #pragma unroll
    for (int t = 0; t < WS; ++t) us[t] = f2h(W[t]);
    us[11] = 0;
    float alpha = 0.f;
    #pragma unroll
    for (int t = 0; t < WS; ++t) alpha += h2f(us[t]);
    uint pe[6], po[6];
    #pragma unroll
    for (int j = 0; j < 6; ++j) {
        pe[j] = (uint)us[2*j] | ((uint)us[2*j+1] << 16);
        po[j] = (j ? (uint)us[2*j-1] : 0u) | ((uint)us[2*j] << 16);
    }

    // ---------- Phase 1: horizontal conv on MFMA (waves 0..2) ---------------
    if (wid < 3) {
        const int rbBase   = (wid == 0) ? 0 : (wid == 1) ? 32 : 42;
        const int pairBase = rbBase >> 1;            // 0, 16, 21
        const int gy = by * TH + rbBase + col - 5;
        const bool rowOK = (unsigned)gy < IMG;
        const float* r1 = p1 + (size_t)gy * IMG;
        const float* r2 = p2 + (size_t)gy * IMG;

        // precomputed B-fragments: 3 x uint4 broadcast loads
        const uint4* gB = (const uint4*)gwB;
        const uint4 Bq[3] = { gB[0*64 + lane], gB[1*64 + lane], gB[2*64 + lane] };

        // x-fragments: [img][T][word], word = f16 cols (2w, 2w+1) of the 8-col lane chunk
        uint xw[2][3][4];
        #pragma unroll
        for (int T = 0; T < 3; ++T) {
            const int gx0 = bx * TW - 8 + 16 * T + 8 * h;   // 4-aligned
            float4 qa = make_float4(0.f,0.f,0.f,0.f), qb = qa, qc = qa, qd = qa;
            if (rowOK && (unsigned)gx0 < IMG)       { qa = *(const float4*)(r1 + gx0);     qc = *(const float4*)(r2 + gx0); }
            if (rowOK && (unsigned)(gx0 + 4) < IMG) { qb = *(const float4*)(r1 + gx0 + 4); qd = *(const float4*)(r2 + gx0 + 4); }
            xw[0][T][0] = pkh(qa.x,qa.y); xw[0][T][1] = pkh(qa.z,qa.w);
            xw[0][T][2] = pkh(qb.x,qb.y); xw[0][T][3] = pkh(qb.z,qb.w);
            xw[1][T][0] = pkh(qc.x,qc.y); xw[1][T][1] = pkh(qc.z,qc.w);
            xw[1][T][2] = pkh(qd.x,qd.y); xw[1][T][3] = pkh(qd.z,qd.w);
        }

        #pragma unroll
        for (int s = 0; s < 5; ++s) {
            f32x16 a = {};
            #pragma unroll
            for (int T = 0; T < 3; ++T) {
                union { uint u[4]; f16x8 v; } A, B;
                if      (s == 0) { A.u[0]=xw[0][T][0]; A.u[1]=xw[0][T][1]; A.u[2]=xw[0][T][2]; A.u[3]=xw[0][T][3]; }
                else if (s == 1) { A.u[0]=xw[1][T][0]; A.u[1]=xw[1][T][1]; A.u[2]=xw[1][T][2]; A.u[3]=xw[1][T][3]; }
                else if (s == 2) { A.u[0]=pkmul(xw[0][T][0],xw[0][T][0]); A.u[1]=pkmul(xw[0][T][1],xw[0][T][1]);
                                   A.u[2]=pkmul(xw[0][T][2],xw[0][T][2]); A.u[3]=pkmul(xw[0][T][3],xw[0][T][3]); }
                else if (s == 3) { A.u[0]=pkmul(xw[1][T][0],xw[1][T][0]); A.u[1]=pkmul(xw[1][T][1],xw[1][T][1]);
                                   A.u[2]=pkmul(xw[1][T][2],xw[1][T][2]); A.u[3]=pkmul(xw[1][T][3],xw[1][T][3]); }
                else             { A.u[0]=pkmul(xw[0][T][0],xw[1][T][0]); A.u[1]=pkmul(xw[0][T][1],xw[1][T][1]);
                                   A.u[2]=pkmul(xw[0][T][2],xw[1][T][2]); A.u[3]=pkmul(xw[0][T][3],xw[1][T][3]); }
                B.u[0]=Bq[T].x; B.u[1]=Bq[T].y; B.u[2]=Bq[T].z; B.u[3]=Bq[T].w;
                a = __builtin_amdgcn_mfma_f32_32x32x16_f16(A.v, B.v, a, 0, 0, 0);
            }
            // D: col=lane&31, row=(reg&3)+8*(reg>>2)+4h -> pack row-pairs, store to HP
            #pragma unroll
            for (int r = 0; r < 8; ++r) {
                constexpr int plist[8] = {0,1,4,5,8,9,12,13};
                const uint wpk = pkh(a[2*r], a[2*r+1]);
                const int p = plist[r] + 2*h + pairBase;
                HP[(s * PR2 + p) * RSTR + col] = wpk;
            }
        }
    }
    __syncthreads();

    // ---------- Phase 2: vertical conv via v_dot2_f32_f16 (validated) -------
    const int q0 = tid >> 3;     // out row-pair (rows 2q0, 2q0+1), 0..31
    const int cg = tid & 7;      // 4-col group

    float m[5][2][4];
    #pragma unroll
    for (int s = 0; s < 5; ++s)
        #pragma unroll
        for (int pth = 0; pth < 2; ++pth)
            #pragma unroll
            for (int c = 0; c < 4; ++c) m[s][pth][c] = 0.f;

    #pragma unroll
    for (int s = 0; s < 5; ++s) {
        #pragma unroll
        for (int j = 0; j <= 5; ++j) {
            const uint4 v = *(const uint4*)&HP[(s * PR2 + q0 + j) * RSTR + cg * 4];
            const uint vv[4] = {v.x, v.y, v.z, v.w};
            #pragma unroll
            for (int c = 0; c < 4; ++c) {
                DOT(m[s][0][c], vv[c], pe[j]);
                DOT(m[s][1][c], vv[c], po[j]);
            }
        }
    }

    // ---------- Epilogue: alpha^2 correction + SSIM for 8 px ----------------
    const float invA = 1.0f / alpha;
    const float invA2 = invA * invA;
    const float C1 = 0.01f*0.01f, C2 = 0.03f*0.03f;
    float lsum = 0.f;
    #pragma unroll
    for (int pth = 0; pth < 2; ++pth) {
        #pragma unroll
        for (int c = 0; c < 4; ++c) {
            const float mu1 = m[0][pth][c] * invA2, mu2 = m[1][pth][c] * invA2;
            const float m11 = m[2][pth][c] * invA2, m22 = m[3][pth][c] * invA2;
            const float m12 = m[4][pth][c] * invA2;
            const float mu1s = mu1*mu1, mu2s = mu2*mu2, mu12 = mu1*mu2;
            const float s11 = m11 - mu1s;
            const float s22 = m22 - mu2s;
            const float s12 = m12 - mu12;
            const float num = (2.f*mu12 + C1) * (2.f*s12 + C2);
            const float den = (mu1s + mu2s + C1) * (s11 + s22 + C2);
            lsum += num * __builtin_amdgcn_rcpf(den);
        }
    }

    // wave reduce + block reduce + spread atomic
    #pragma unroll
    for (int d = 32; d >= 1; d >>= 1)
        lsum += __shfl_down(lsum, d, 64);
    __shared__ float wsum[4];
    if ((tid & 63) == 0) wsum[tid >> 6] = lsum;
    __syncthreads();
    if (tid == 0) {
        const float t = wsum[0] + wsum[1] + wsum[2] + wsum[3];
        const int bid = (blockIdx.z * gridDim.y + blockIdx.y) * gridDim.x + blockIdx.x;
        atomicAdd(&acc[bid & (NSLOT - 1)], (double)t);
    }
}

__global__ void ssim_final(const double* __restrict__ acc, float* __restrict__ out) {
    const int l = threadIdx.x;   // 64 threads
    double s = acc[l] + acc[l + 64] + acc[l + 128] + acc[l + 192];
    #pragma unroll
    for (int d = 32; d >= 1; d >>= 1)
        s += __shfl_down(s, d, 64);
    if (l == 0)
        out[0] = 1.0f - (float)(s / (double)((size_t)NP * IMG * IMG));
}

extern "C" void kernel_launch(void* const* d_in, const int* in_sizes, int n_in,
                              void* d_out, int out_size, void* d_ws, size_t ws_size,
                              hipStream_t stream) {
    const float* img1 = (const float*)d_in[0];
    const float* img2 = (const float*)d_in[1];
    float* out = (float*)d_out;
    double* acc = (double*)d_ws;
    uint* gwB = (uint*)((char*)d_ws + NSLOT * sizeof(double));

    hipMemsetAsync(d_ws, 0, NSLOT * sizeof(double), stream);
    build_gh<<<1, 64, 0, stream>>>(gwB);

    dim3 grid(IMG / TW, IMG / TH, NP);
    ssim_main<<<grid, dim3(256), 0, stream>>>(img1, img2, gwB, acc);
    ssim_final<<<1, dim3(64), 0, stream>>>(acc, out);
}

// Round 17
// 110.619 us; speedup vs baseline: 1.1991x; 1.1991x over previous
//
#include <hip/hip_runtime.h>
#include <hip/hip_fp16.h>

#define IMG   512
#define TW    32
#define TH    64
#define WS    11
#define NP    96
#define NSLOT 256
#define PR2   37            // pair-rows (74 h-conv rows as f16 pairs)
#define RSTR  32            // u32 row stride
#define PLANE (PR2*RSTR)    // u32 words per signal plane (1184)

typedef _Float16 h2v __attribute__((ext_vector_type(2)));

static __device__ __forceinline__ uint pkh(float ev, float od) {
    return __builtin_bit_cast(uint, __builtin_amdgcn_cvt_pkrtz(ev, od));
}
static __device__ __forceinline__ ushort f2h(float x) {
    return __builtin_bit_cast(ushort, (_Float16)x);
}
static __device__ __forceinline__ float h2f(ushort u) {
    return (float)__builtin_bit_cast(_Float16, u);
}
static __device__ __forceinline__ uint pkmul(uint a, uint b) {
    const h2v r = __builtin_bit_cast(h2v, a) * __builtin_bit_cast(h2v, b); // v_pk_mul_f16
    return __builtin_bit_cast(uint, r);
}

#define DOT(ACC, VW, WT) \
    asm("v_dot2_f32_f16 %0, %1, %2, %0" : "+v"(ACC) : "v"(VW), "v"(WT))

__global__ __launch_bounds__(256, 5) void ssim_main(const float* __restrict__ img1,
                                                    const float* __restrict__ img2,
                                                    double* __restrict__ acc) {
    constexpr float W[WS] = {
        0.00102837990674f, 0.00759883148699f, 0.03600079242909f,
        0.10936069869137f, 0.21300538108707f, 0.26601190869814f,
        0.21300538108707f, 0.10936069869137f, 0.03600079242909f,
        0.00759883148699f, 0.00102837990674f };

    // 5 signal planes, f16 row-pairs: HP[(s*PR2+p)*32 + col] = h(H[2p]) | h(H[2p+1])<<16
    __shared__ uint HP[5 * PLANE];   // 23,680 B -> 6 blocks/CU LDS-wise

    const int tid = threadIdx.x;
    const int bx = blockIdx.x;   // 0..15 (x tiles, 32 wide)
    const int by = blockIdx.y;   // 0..7  (y tiles, 64 tall)
    const float* p1 = img1 + (size_t)blockIdx.z * (IMG * IMG);
    const float* p2 = img2 + (size_t)blockIdx.z * (IMG * IMG);

    // f16-rounded weights; pe[j] = taps(2j,2j+1), po[j] = taps(2j-1,2j); alpha = sum
    ushort us[12];
    #pragma unroll
    for (int t = 0; t < WS; ++t) us[t] = f2h(W[t]);
    us[11] = 0;
    float alpha = 0.f;
    #pragma unroll
    for (int t = 0; t < WS; ++t) alpha += h2f(us[t]);
    uint pe[6], po[6];
    #pragma unroll
    for (int j = 0; j < 6; ++j) {
        pe[j] = (uint)us[2*j] | ((uint)us[2*j+1] << 16);
        po[j] = (j ? (uint)us[2*j-1] : 0u) | ((uint)us[2*j] << 16);
    }

    // ---------- Phase 1: horizontal conv via v_dot2_f32_f16 -----------------
    // unit = (pair-row pr, 4-col group cg); out cols c0..c0+3, c0 = cg*4 (even)
    for (int u = tid; u < PR2 * 8; u += 256) {        // 296 units
        const int pr = u >> 3;
        const int cg = u & 7;
        const int gy0 = by * TH + 2 * pr - 5;

        float A[5][2][4];
        #pragma unroll
        for (int s = 0; s < 5; ++s)
            #pragma unroll
            for (int rw = 0; rw < 2; ++rw)
                #pragma unroll
                for (int o = 0; o < 4; ++o) A[s][rw][o] = 0.f;

        #pragma unroll
        for (int rw = 0; rw < 2; ++rw) {
            const int gy = gy0 + rw;
            const bool rowOK = (unsigned)gy < IMG;
            const float* r1 = p1 + (size_t)gy * IMG;
            const float* r2 = p2 + (size_t)gy * IMG;

            // load 20 cols (c0-8..c0+11), pack words w[i] = cols (c0-6+2i, c0-5+2i)
            float e1[20], e2[20];
            #pragma unroll
            for (int j = 0; j < 5; ++j) {
                const int gx = bx * TW + cg * 4 - 8 + 4 * j;
                float4 X = make_float4(0.f,0.f,0.f,0.f), Y = X;
                if (rowOK && (unsigned)gx < IMG) {
                    X = *(const float4*)(r1 + gx);
                    Y = *(const float4*)(r2 + gx);
                }
                e1[4*j+0]=X.x; e1[4*j+1]=X.y; e1[4*j+2]=X.z; e1[4*j+3]=X.w;
                e2[4*j+0]=Y.x; e2[4*j+1]=Y.y; e2[4*j+2]=Y.z; e2[4*j+3]=Y.w;
            }
            uint x1w[8], x2w[8];
            #pragma unroll
            for (int i = 0; i < 8; ++i) {
                x1w[i] = pkh(e1[2+2*i], e1[3+2*i]);
                x2w[i] = pkh(e2[2+2*i], e2[3+2*i]);
            }

            // linear signals
            #pragma unroll
            for (int j = 0; j < 6; ++j) {
                DOT(A[0][rw][0], x1w[j],   po[j]);
                DOT(A[0][rw][1], x1w[j+1], pe[j]);
                DOT(A[0][rw][2], x1w[j+1], po[j]);
                DOT(A[0][rw][3], x1w[j+2], pe[j]);
                DOT(A[1][rw][0], x2w[j],   po[j]);
                DOT(A[1][rw][1], x2w[j+1], pe[j]);
                DOT(A[1][rw][2], x2w[j+1], po[j]);
                DOT(A[1][rw][3], x2w[j+2], pe[j]);
            }
            // quadratic signals (packed f16 muls, transient)
            uint q11w[8], q22w[8], q12w[8];
            #pragma unroll
            for (int i = 0; i < 8; ++i) {
                q11w[i] = pkmul(x1w[i], x1w[i]);
                q22w[i] = pkmul(x2w[i], x2w[i]);
                q12w[i] = pkmul(x1w[i], x2w[i]);
            }
            #pragma unroll
            for (int j = 0; j < 6; ++j) {
                DOT(A[2][rw][0], q11w[j],   po[j]);
                DOT(A[2][rw][1], q11w[j+1], pe[j]);
                DOT(A[2][rw][2], q11w[j+1], po[j]);
                DOT(A[2][rw][3], q11w[j+2], pe[j]);
                DOT(A[3][rw][0], q22w[j],   po[j]);
                DOT(A[3][rw][1], q22w[j+1], pe[j]);
                DOT(A[3][rw][2], q22w[j+1], po[j]);
                DOT(A[3][rw][3], q22w[j+2], pe[j]);
                DOT(A[4][rw][0], q12w[j],   po[j]);
                DOT(A[4][rw][1], q12w[j+1], pe[j]);
                DOT(A[4][rw][2], q12w[j+1], po[j]);
                DOT(A[4][rw][3], q12w[j+2], pe[j]);
            }
        }

        #pragma unroll
        for (int s = 0; s < 5; ++s) {
            const uint4 pv = make_uint4(pkh(A[s][0][0], A[s][1][0]),
                                        pkh(A[s][0][1], A[s][1][1]),
                                        pkh(A[s][0][2], A[s][1][2]),
                                        pkh(A[s][0][3], A[s][1][3]));
            *(uint4*)&HP[(s * PR2 + pr) * RSTR + cg * 4] = pv;
        }
    }
    __syncthreads();

    // ---------- Phase 2: vertical conv via v_dot2_f32_f16 -------------------
    const int q0 = tid >> 3;     // out row-pair (rows 2q0, 2q0+1), 0..31
    const int cg = tid & 7;      // 4-col group

    float m[5][2][4];
    #pragma unroll
    for (int s = 0; s < 5; ++s)
        #pragma unroll
        for (int pth = 0; pth < 2; ++pth)
            #pragma unroll
            for (int c = 0; c < 4; ++c) m[s][pth][c] = 0.f;

    #pragma unroll
    for (int s = 0; s < 5; ++s) {
        #pragma unroll
        for (int j = 0; j <= 5; ++j) {
            const uint4 v = *(const uint4*)&HP[(s * PR2 + q0 + j) * RSTR + cg * 4];
            const uint vv[4] = {v.x, v.y, v.z, v.w};
            #pragma unroll
            for (int c = 0; c < 4; ++c) {
                DOT(m[s][0][c], vv[c], pe[j]);
                DOT(m[s][1][c], vv[c], po[j]);
            }
        }
    }

    // ---------- Epilogue: alpha^2 correction + SSIM for 8 px ----------------
    const float invA = 1.0f / alpha;
    const float invA2 = invA * invA;
    const float C1 = 0.01f*0.01f, C2 = 0.03f*0.03f;
    float lsum = 0.f;
    #pragma unroll
    for (int pth = 0; pth < 2; ++pth) {
        #pragma unroll
        for (int c = 0; c < 4; ++c) {
            const float mu1 = m[0][pth][c] * invA2, mu2 = m[1][pth][c] * invA2;
            const float m11 = m[2][pth][c] * invA2, m22 = m[3][pth][c] * invA2;
            const float m12 = m[4][pth][c] * invA2;
            const float mu1s = mu1*mu1, mu2s = mu2*mu2, mu12 = mu1*mu2;
            const float s11 = m11 - mu1s;
            const float s22 = m22 - mu2s;
            const float s12 = m12 - mu12;
            const float num = (2.f*mu12 + C1) * (2.f*s12 + C2);
            const float den = (mu1s + mu2s + C1) * (s11 + s22 + C2);
            lsum += num * __builtin_amdgcn_rcpf(den);
        }
    }

    // wave reduce + block reduce + spread atomic
    #pragma unroll
    for (int d = 32; d >= 1; d >>= 1)
        lsum += __shfl_down(lsum, d, 64);
    __shared__ float wsum[4];
    if ((tid & 63) == 0) wsum[tid >> 6] = lsum;
    __syncthreads();
    if (tid == 0) {
        const float t = wsum[0] + wsum[1] + wsum[2] + wsum[3];
        const int bid = (blockIdx.z * gridDim.y + blockIdx.y) * gridDim.x + blockIdx.x;
        atomicAdd(&acc[bid & (NSLOT - 1)], (double)t);
    }
}

__global__ void ssim_final(const double* __restrict__ acc, float* __restrict__ out) {
    const int l = threadIdx.x;   // 64 threads
    double s = acc[l] + acc[l + 64] + acc[l + 128] + acc[l + 192];
    #pragma unroll
    for (int d = 32; d >= 1; d >>= 1)
        s += __shfl_down(s, d, 64);
    if (l == 0)
        out[0] = 1.0f - (float)(s / (double)((size_t)NP * IMG * IMG));
}

extern "C" void kernel_launch(void* const* d_in, const int* in_sizes, int n_in,
                              void* d_out, int out_size, void* d_ws, size_t ws_size,
                              hipStream_t stream) {
    const float* img1 = (const float*)d_in[0];
    const float* img2 = (const float*)d_in[1];
    float* out = (float*)d_out;
    double* acc = (double*)d_ws;

    hipMemsetAsync(d_ws, 0, NSLOT * sizeof(double), stream);

    dim3 grid(IMG / TW, IMG / TH, NP);
    ssim_main<<<grid, dim3(256), 0, stream>>>(img1, img2, acc);
    ssim_final<<<1, dim3(64), 0, stream>>>(acc, out);
}

// Round 18
// 107.722 us; speedup vs baseline: 1.2314x; 1.0269x over previous
//
#include <hip/hip_runtime.h>
#include <hip/hip_fp16.h>

#define IMG   512
#define TW    32
#define TH    64
#define WS    11
#define NP    96
#define NSLOT 256
#define PR2   37            // pair-rows (74 h-conv rows as f16 pairs)
#define RSTR  32            // u32 row stride
#define PLANE (PR2*RSTR)    // u32 words per signal plane (1184)

typedef _Float16 h2v __attribute__((ext_vector_type(2)));

static __device__ __forceinline__ uint pkh(float ev, float od) {
    return __builtin_bit_cast(uint, __builtin_amdgcn_cvt_pkrtz(ev, od));
}
static __device__ __forceinline__ ushort f2h(float x) {
    return __builtin_bit_cast(ushort, (_Float16)x);
}
static __device__ __forceinline__ float h2f(ushort u) {
    return (float)__builtin_bit_cast(_Float16, u);
}

__global__ __launch_bounds__(256, 4) void ssim_main(const float* __restrict__ img1,
                                                    const float* __restrict__ img2,
                                                    double* __restrict__ acc) {
    constexpr float W[WS] = {
        0.00102837990674f, 0.00759883148699f, 0.03600079242909f,
        0.10936069869137f, 0.21300538108707f, 0.26601190869814f,
        0.21300538108707f, 0.10936069869137f, 0.03600079242909f,
        0.00759883148699f, 0.00102837990674f };

    // 5 signal planes, f16 row-pairs: HP[(s*PR2+p)*32 + col] = h(H[2p]) | h(H[2p+1])<<16
    __shared__ uint HP[5 * PLANE];   // 23,680 B

    const int tid = threadIdx.x;
    const int bx = blockIdx.x;   // 0..15 (x tiles, 32 wide)
    const int by = blockIdx.y;   // 0..7  (y tiles, 64 tall)
    const float* p1 = img1 + (size_t)blockIdx.z * (IMG * IMG);
    const float* p2 = img2 + (size_t)blockIdx.z * (IMG * IMG);

    // f16-rounded vertical weights, packed pairs for dot2; alpha = their sum
    ushort us[12];
    #pragma unroll
    for (int t = 0; t < WS; ++t) us[t] = f2h(W[t]);
    us[11] = 0;
    float alpha = 0.f;
    #pragma unroll
    for (int t = 0; t < WS; ++t) alpha += h2f(us[t]);
    uint pe[6], po[6];
    #pragma unroll
    for (int j = 0; j < 6; ++j) {
        pe[j] = (uint)us[2*j] | ((uint)us[2*j+1] << 16);            // even out-row: taps 2j, 2j+1
        po[j] = (j ? (uint)us[2*j-1] : 0u) | ((uint)us[2*j] << 16); // odd out-row: taps 2j-1, 2j
    }

    // ---------- Phase 1: horizontal conv (f32), 2 rows x 4 cols per unit ----
    for (int u = tid; u < PR2 * 8; u += 256) {        // 296 units
        const int pr = u >> 3;        // pair-row 0..36
        const int cg = u & 7;         // 4-col group

        float A[5][2][4];
        #pragma unroll
        for (int s = 0; s < 5; ++s)
            #pragma unroll
            for (int rw = 0; rw < 2; ++rw)
                #pragma unroll
                for (int o = 0; o < 4; ++o) A[s][rw][o] = 0.f;

        #pragma unroll
        for (int rw = 0; rw < 2; ++rw) {
            const int gy = by * TH + 2 * pr + rw - 5;
            const bool rowOK = (unsigned)gy < IMG;
            const float* r1 = p1 + (size_t)gy * IMG;
            const float* r2 = p2 + (size_t)gy * IMG;
            #pragma unroll
            for (int j = 0; j < 5; ++j) {
                const int gx = bx * TW + cg * 4 - 8 + 4 * j;
                float4 X = make_float4(0.f,0.f,0.f,0.f), Y = X;
                if (rowOK && (unsigned)gx < IMG) {
                    X = *(const float4*)(r1 + gx);
                    Y = *(const float4*)(r2 + gx);
                }
                const float e1[4] = {X.x,X.y,X.z,X.w};
                const float e2[4] = {Y.x,Y.y,Y.z,Y.w};
                #pragma unroll
                for (int e = 0; e < 4; ++e) {
                    const int i = 4*j + e;            // taps live 3..16
                    if (i < 3 || i > 16) continue;
                    const float x1 = e1[e], x2 = e2[e];
                    const float q11 = x1*x1, q22 = x2*x2, q12 = x1*x2;
                    #pragma unroll
                    for (int o = 0; o < 4; ++o) {
                        const int t = i - 3 - o;
                        if (t >= 0 && t < WS) {
                            A[0][rw][o] += W[t]*x1;  A[1][rw][o] += W[t]*x2;
                            A[2][rw][o] += W[t]*q11; A[3][rw][o] += W[t]*q22;
                            A[4][rw][o] += W[t]*q12;
                        }
                    }
                }
            }
        }

        #pragma unroll
        for (int s = 0; s < 5; ++s) {
            const uint4 pv = make_uint4(pkh(A[s][0][0], A[s][1][0]),
                                        pkh(A[s][0][1], A[s][1][1]),
                                        pkh(A[s][0][2], A[s][1][2]),
                                        pkh(A[s][0][3], A[s][1][3]));
            *(uint4*)&HP[(s * PR2 + pr) * RSTR + cg * 4] = pv;
        }
    }
    __syncthreads();

    // ---------- Phase 2: vertical conv via v_dot2_f32_f16 -------------------
    const int q0 = tid >> 3;     // out row-pair (rows 2q0, 2q0+1), 0..31
    const int cg = tid & 7;      // 4-col group

    float m[5][2][4];
    #pragma unroll
    for (int s = 0; s < 5; ++s)
        #pragma unroll
        for (int pth = 0; pth < 2; ++pth)
            #pragma unroll
            for (int c = 0; c < 4; ++c) m[s][pth][c] = 0.f;

    #pragma unroll
    for (int s = 0; s < 5; ++s) {
        #pragma unroll
        for (int j = 0; j <= 5; ++j) {
            const uint4 v = *(const uint4*)&HP[(s * PR2 + q0 + j) * RSTR + cg * 4];
            const uint vv[4] = {v.x, v.y, v.z, v.w};
            #pragma unroll
            for (int c = 0; c < 4; ++c) {
                asm("v_dot2_f32_f16 %0, %1, %2, %0"
                    : "+v"(m[s][0][c]) : "v"(vv[c]), "v"(pe[j]));
                asm("v_dot2_f32_f16 %0, %1, %2, %0"
                    : "+v"(m[s][1][c]) : "v"(vv[c]), "v"(po[j]));
            }
        }
    }

    // ---------- Epilogue: kernel-sum correction + SSIM for 8 px -------------
    const float invA = 1.0f / alpha;
    const float C1 = 0.01f*0.01f, C2 = 0.03f*0.03f;
    float lsum = 0.f;
    #pragma unroll
    for (int pth = 0; pth < 2; ++pth) {
        #pragma unroll
        for (int c = 0; c < 4; ++c) {
            const float mu1 = m[0][pth][c] * invA, mu2 = m[1][pth][c] * invA;
            const float m11 = m[2][pth][c] * invA, m22 = m[3][pth][c] * invA;
            const float m12 = m[4][pth][c] * invA;
            const float mu1s = mu1*mu1, mu2s = mu2*mu2, mu12 = mu1*mu2;
            const float s11 = m11 - mu1s;
            const float s22 = m22 - mu2s;
            const float s12 = m12 - mu12;
            const float num = (2.f*mu12 + C1) * (2.f*s12 + C2);
            const float den = (mu1s + mu2s + C1) * (s11 + s22 + C2);
            lsum += num * __builtin_amdgcn_rcpf(den);
        }
    }

    // wave reduce + block reduce + spread atomic
    #pragma unroll
    for (int d = 32; d >= 1; d >>= 1)
        lsum += __shfl_down(lsum, d, 64);
    __shared__ float wsum[4];
    if ((tid & 63) == 0) wsum[tid >> 6] = lsum;
    __syncthreads();
    if (tid == 0) {
        const float t = wsum[0] + wsum[1] + wsum[2] + wsum[3];
        const int bid = (blockIdx.z * gridDim.y + blockIdx.y) * gridDim.x + blockIdx.x;
        atomicAdd(&acc[bid & (NSLOT - 1)], (double)t);
    }
}

__global__ void ssim_final(const double* __restrict__ acc, float* __restrict__ out) {
    const int l = threadIdx.x;   // 64 threads
    double s = acc[l] + acc[l + 64] + acc[l + 128] + acc[l + 192];
    #pragma unroll
    for (int d = 32; d >= 1; d >>= 1)
        s += __shfl_down(s, d, 64);
    if (l == 0)
        out[0] = 1.0f - (float)(s / (double)((size_t)NP * IMG * IMG));
}

extern "C" void kernel_launch(void* const* d_in, const int* in_sizes, int n_in,
                              void* d_out, int out_size, void* d_ws, size_t ws_size,
                              hipStream_t stream) {
    const float* img1 = (const float*)d_in[0];
    const float* img2 = (const float*)d_in[1];
    float* out = (float*)d_out;
    double* acc = (double*)d_ws;

    hipMemsetAsync(d_ws, 0, NSLOT * sizeof(double), stream);

    dim3 grid(IMG / TW, IMG / TH, NP);
    ssim_main<<<grid, dim3(256), 0, stream>>>(img1, img2, acc);
    ssim_final<<<1, dim3(64), 0, stream>>>(acc, out);
}